// Round 2
// baseline (133.711 us; speedup 1.0000x reference)
//
#include <hip/hip_runtime.h>
#include <math.h>

#define BS 8
#define NR 60
#define NP 500
#define NHW 6400
#define NPAIR (BS*NR)         // 480 (b,r) pairs
#define NBLK (NPAIR*2)        // 960 blocks, 2 per pair (n-halves of 250)
#define NT_ELEMS (BS*NP*3)    // 12000
#define LT_PER_BLK 25         // 480*25 = 12000 (h==0 blocks only)

// Pack target points as float4 {x,y,z,|t|^2}: hot loop = one uniform s_load + 5 VALU/pt.
__global__ __launch_bounds__(256) void pack_tgt(const float* __restrict__ target_r,
                                                float4* __restrict__ t4) {
    int i = blockIdx.x * blockDim.x + threadIdx.x;
    if (i < BS * NP) {
        const float* p = target_r + i * 3;
        float x = p[0], y = p[1], z = p[2];
        t4[i] = make_float4(x, y, z, x * x + y * y + z * z);
    }
}

__global__ __launch_bounds__(256) void main_kernel(
    const float* __restrict__ pred_t,        // (8,500,3)
    const float* __restrict__ pred_r,        // (8,60,4)
    const float* __restrict__ target_t,      // (8,3,6400)
    const float* __restrict__ model_points,  // (8,1,500,3)
    const int*   __restrict__ choose,        // (8,500)
    const float* __restrict__ rot_anchors,   // (60,4)
    const float4* __restrict__ t4g,          // ws: (8,500) packed targets
    float* __restrict__ out_sym,             // 960 per-block sums
    float* __restrict__ out_non,             // 960
    float* __restrict__ out_reg,             // 480 (h==0 blocks)
    float* __restrict__ out_lt)              // 480 (h==0 blocks)
{
    const int bid  = blockIdx.x;
    const int pair = bid >> 1;       // (b,r)
    const int h    = bid & 1;        // n-half
    const int b = pair / NR;
    const int r = pair % NR;
    const int tid = threadIdx.x;

    __shared__ float red[8];

    // --- quaternion -> rotation (reference formula, raw unnormalized q) ---
    const float* q = pred_r + pair * 4;
    const float w = q[0], x = q[1], y = q[2], z = q[3];
    const float r00 = 1.f - 2.f * (y * y + z * z);
    const float r01 = 2.f * x * y - 2.f * w * z;
    const float r02 = 2.f * w * y + 2.f * x * z;
    const float r10 = 2.f * x * y + 2.f * z * w;
    const float r11 = 1.f - 2.f * (x * x + z * z);
    const float r12 = -2.f * w * x + 2.f * y * z;
    const float r20 = -2.f * w * y + 2.f * x * z;
    const float r21 = 2.f * w * x + 2.f * y * z;
    const float r22 = 1.f - 2.f * (x * x + y * y);

    // --- loss_t partial (h==0 blocks): 25 scattered elems per pair ---
    float lt = 0.f;
    if (h == 0 && tid < LT_PER_BLK) {
        int e = pair * LT_PER_BLK + tid;     // flat index into pred_t (8,500,3)
        int bb = e / 1500;
        int rem = e - bb * 1500;
        int n = rem / 3;
        int k = rem - n * 3;
        int pos = choose[bb * NP + n];
        float ts = target_t[(bb * 3 + k) * NHW + pos];
        float diff = pred_t[e] - ts;
        float ad = fabsf(diff);
        lt = (ad < 1.f) ? 0.5f * diff * diff : ad - 0.5f;
    }

    // --- reg term (h==0, wave 0): lane a = dot(q, anchor_a) ---
    if (h == 0 && tid < 64) {
        float dot = -3.4e38f;
        if (tid < NR) {
            const float* an = rot_anchors + tid * 4;
            dot = w * an[0] + x * an[1] + y * an[2] + z * an[3];
        }
        float diag = __shfl(dot, r, 64);
        float mx = dot;
        for (int o = 32; o > 0; o >>= 1) mx = fmaxf(mx, __shfl_down(mx, o, 64));
        for (int o = 32; o > 0; o >>= 1) lt += __shfl_down(lt, o, 64);
        if (tid == 0) {
            float rg = mx - diag;
            out_reg[pair] = (rg > 0.001f) ? rg : 0.f;
            out_lt[pair] = lt;
        }
    }

    // --- chamfer: one model point per thread (250 active per block) ---
    const int n0 = h * 250 + tid;
    const bool active = (tid < 250);
    const int nc = active ? n0 : 0;          // clamped index for inactive lanes

    const float* mpb = model_points + b * NP * 3;
    const float mx_ = mpb[nc * 3 + 0], my_ = mpb[nc * 3 + 1], mz_ = mpb[nc * 3 + 2];

    const float px = r00 * mx_ + r01 * my_ + r02 * mz_;
    const float py = r10 * mx_ + r11 * my_ + r12 * mz_;
    const float pz = r20 * mx_ + r21 * my_ + r22 * mz_;
    const float a2 = px * px + py * py + pz * pz;

    const float4* __restrict__ t4 = t4g + b * NP;
    // 4 independent min accumulators: break the loop-carried v_min chain.
    float mnA = 3.4e38f, mnB = 3.4e38f, mnC = 3.4e38f, mnD = 3.4e38f;
    for (int m = 0; m < NP; m += 4) {
        float4 tA = t4[m + 0];
        float4 tB = t4[m + 1];
        float4 tC = t4[m + 2];
        float4 tD = t4[m + 3];
        float dA = fmaf(px, tA.x, fmaf(py, tA.y, pz * tA.z));
        float dB = fmaf(px, tB.x, fmaf(py, tB.y, pz * tB.z));
        float dC = fmaf(px, tC.x, fmaf(py, tC.y, pz * tC.z));
        float dD = fmaf(px, tD.x, fmaf(py, tD.y, pz * tD.z));
        mnA = fminf(mnA, fmaf(-2.f, dA, tA.w));
        mnB = fminf(mnB, fmaf(-2.f, dB, tB.w));
        mnC = fminf(mnC, fmaf(-2.f, dC, tC.w));
        mnD = fminf(mnD, fmaf(-2.f, dD, tD.w));
    }
    const float mn = fminf(fminf(mnA, mnB), fminf(mnC, mnD));

    float ssym = 0.f, snon = 0.f;
    if (active) {
        float d2 = fmaxf(a2 + mn, 1e-12f);
        ssym = sqrtf(d2);
        float4 t = t4[nc];
        float dx = px - t.x, dy = py - t.y, dz = pz - t.z;
        snon = sqrtf(dx * dx + dy * dy + dz * dz);
    }

    // --- block reduce (4 waves) ---
    for (int o = 32; o > 0; o >>= 1) {
        ssym += __shfl_down(ssym, o, 64);
        snon += __shfl_down(snon, o, 64);
    }
    const int wv = tid >> 6, ln = tid & 63;
    if (ln == 0) { red[wv] = ssym; red[4 + wv] = snon; }
    __syncthreads();
    if (tid == 0) {
        out_sym[bid] = red[0] + red[1] + red[2] + red[3];
        out_non[bid] = red[4] + red[5] + red[6] + red[7];
    }
}

__global__ __launch_bounds__(256) void finalize_kernel(
    const float* __restrict__ out_sym, const float* __restrict__ out_non,
    const float* __restrict__ out_reg, const float* __restrict__ out_lt,
    const float* __restrict__ pred_c,
    const unsigned char* __restrict__ symU8, const int* __restrict__ symI,
    const float* __restrict__ diam, float* __restrict__ out)
{
    const int tid = threadIdx.x;
    float s_r = 0.f, s_reg = 0.f, s_t = 0.f;
    for (int i = tid; i < NPAIR; i += 256) {
        int b = i / NR;
        // layout-agnostic bool read: true under both 1-byte-bool and int32 storage
        bool sym = (symU8[b] != 0) || (symI[b] != 0);
        float sum = sym ? (out_sym[2 * i] + out_sym[2 * i + 1])
                        : (out_non[2 * i] + out_non[2 * i + 1]);
        float d = sum * (1.0f / NP);
        float c = pred_c[i];
        s_r += (d / (diam[b] * c) + logf(c)) * (1.0f / NR);
        s_reg += out_reg[i];
        s_t += out_lt[i];
    }
    __shared__ float red[12];
    for (int o = 32; o > 0; o >>= 1) {
        s_r += __shfl_down(s_r, o, 64);
        s_reg += __shfl_down(s_reg, o, 64);
        s_t += __shfl_down(s_t, o, 64);
    }
    const int wv = tid >> 6, ln = tid & 63;
    if (ln == 0) { red[wv] = s_r; red[4 + wv] = s_reg; red[8 + wv] = s_t; }
    __syncthreads();
    if (tid == 0) {
        float lr = red[0] + red[1] + red[2] + red[3];
        float lreg = (red[4] + red[5] + red[6] + red[7]) * (1.0f / NPAIR);
        float ltv = (red[8] + red[9] + red[10] + red[11]) * (1.0f / NT_ELEMS);
        out[0] = lr + 2.f * lreg + 5.f * ltv;
        out[1] = lr;
        out[2] = lreg;
        out[3] = ltv;
    }
}

extern "C" void kernel_launch(void* const* d_in, const int* in_sizes, int n_in,
                              void* d_out, int out_size, void* d_ws, size_t ws_size,
                              hipStream_t stream) {
    const float* pred_t       = (const float*)d_in[0];
    const float* pred_r       = (const float*)d_in[1];
    const float* pred_c       = (const float*)d_in[2];
    const float* target_r     = (const float*)d_in[3];
    const float* target_t     = (const float*)d_in[4];
    const float* model_points = (const float*)d_in[5];
    const int*   choose       = (const int*)d_in[6];
    const unsigned char* symU8 = (const unsigned char*)d_in[7];
    const int*   symI         = (const int*)d_in[7];
    const float* diam         = (const float*)d_in[8];
    const float* anchors      = (const float*)d_in[9];
    float* out = (float*)d_out;

    char* ws = (char*)d_ws;
    float4* t4  = (float4*)ws;                        // 8*500*16 = 64000 B
    float* o_sym = (float*)(ws + 64000);              // 960 floats
    float* o_non = o_sym + NBLK;                      // 960
    float* o_reg = o_non + NBLK;                      // 480
    float* o_lt  = o_reg + NPAIR;                     // 480

    pack_tgt<<<(BS * NP + 255) / 256, 256, 0, stream>>>(target_r, t4);
    main_kernel<<<NBLK, 256, 0, stream>>>(pred_t, pred_r, target_t, model_points,
                                          choose, anchors, t4,
                                          o_sym, o_non, o_reg, o_lt);
    finalize_kernel<<<1, 256, 0, stream>>>(o_sym, o_non, o_reg, o_lt,
                                           pred_c, symU8, symI, diam, out);
}

// Round 3
// 95.473 us; speedup vs baseline: 1.4005x; 1.4005x over previous
//
#include <hip/hip_runtime.h>
#include <math.h>

#define BS 8
#define NR 60
#define NP 500
#define NHW 6400
#define NBLK (BS*NR)          // 480 blocks, one per (b,r)
#define NT_ELEMS (BS*NP*3)    // 12000
#define LT_PER_BLK 25         // 480*25 = 12000

__global__ __launch_bounds__(256) void main_kernel(
    const float* __restrict__ pred_t,        // (8,500,3)
    const float* __restrict__ pred_r,        // (8,60,4)
    const float* __restrict__ target_r,      // (8,1,500,3)
    const float* __restrict__ target_t,      // (8,3,6400)
    const float* __restrict__ model_points,  // (8,1,500,3)
    const int*   __restrict__ choose,        // (8,500)
    const float* __restrict__ rot_anchors,   // (60,4)
    float* __restrict__ out_sym,             // 480 per-block sums
    float* __restrict__ out_non,             // 480
    float* __restrict__ out_reg,             // 480
    float* __restrict__ out_lt)              // 480
{
    const int bid = blockIdx.x;
    const int b = bid / NR;
    const int r = bid % NR;
    const int tid = threadIdx.x;

    __shared__ float4 t4s[NP];               // {x,y,z,|t|^2} — 8000 B
    __shared__ float red[8];

    // --- stage target points global -> LDS, fusing |t|^2 (was pack_tgt) ---
    for (int i = tid; i < NP; i += 256) {
        const float* p = target_r + (b * NP + i) * 3;
        float x = p[0], y = p[1], z = p[2];
        t4s[i] = make_float4(x, y, z, x * x + y * y + z * z);
    }

    // --- quaternion -> rotation (reference formula, raw unnormalized q) ---
    const float* q = pred_r + bid * 4;
    const float w = q[0], x = q[1], y = q[2], z = q[3];
    const float r00 = 1.f - 2.f * (y * y + z * z);
    const float r01 = 2.f * x * y - 2.f * w * z;
    const float r02 = 2.f * w * y + 2.f * x * z;
    const float r10 = 2.f * x * y + 2.f * z * w;
    const float r11 = 1.f - 2.f * (x * x + z * z);
    const float r12 = -2.f * w * x + 2.f * y * z;
    const float r20 = -2.f * w * y + 2.f * x * z;
    const float r21 = 2.f * w * x + 2.f * y * z;
    const float r22 = 1.f - 2.f * (x * x + y * y);

    // --- loss_t partial: 25 scattered elements per block ---
    float lt = 0.f;
    if (tid < LT_PER_BLK) {
        int e = bid * LT_PER_BLK + tid;      // flat index into pred_t (8,500,3)
        int bb = e / 1500;
        int rem = e - bb * 1500;
        int n = rem / 3;
        int k = rem - n * 3;
        int pos = choose[bb * NP + n];
        float ts = target_t[(bb * 3 + k) * NHW + pos];
        float diff = pred_t[e] - ts;
        float ad = fabsf(diff);
        lt = (ad < 1.f) ? 0.5f * diff * diff : ad - 0.5f;
    }

    // --- reg term: wave 0, lane a computes dot(q, anchor_a) ---
    if (tid < 64) {
        float dot = -3.4e38f;
        if (tid < NR) {
            const float* an = rot_anchors + tid * 4;
            dot = w * an[0] + x * an[1] + y * an[2] + z * an[3];
        }
        float diag = __shfl(dot, r, 64);
        float mx = dot;
        for (int o = 32; o > 0; o >>= 1) mx = fmaxf(mx, __shfl_down(mx, o, 64));
        for (int o = 32; o > 0; o >>= 1) lt += __shfl_down(lt, o, 64);
        if (tid == 0) {
            float rg = mx - diag;
            out_reg[bid] = (rg > 0.001f) ? rg : 0.f;
            out_lt[bid] = lt;
        }
    }

    // --- chamfer: each thread owns up to 2 model points ---
    const int n0 = tid;
    const int n1 = tid + 256;
    const bool has1 = (n1 < NP);

    const float* mpb = model_points + b * NP * 3;
    float m0x = mpb[n0 * 3 + 0], m0y = mpb[n0 * 3 + 1], m0z = mpb[n0 * 3 + 2];
    float m1x = 0.f, m1y = 0.f, m1z = 0.f;
    if (has1) { m1x = mpb[n1 * 3 + 0]; m1y = mpb[n1 * 3 + 1]; m1z = mpb[n1 * 3 + 2]; }

    const float p0x = r00 * m0x + r01 * m0y + r02 * m0z;
    const float p0y = r10 * m0x + r11 * m0y + r12 * m0z;
    const float p0z = r20 * m0x + r21 * m0y + r22 * m0z;
    const float p1x = r00 * m1x + r01 * m1y + r02 * m1z;
    const float p1y = r10 * m1x + r11 * m1y + r12 * m1z;
    const float p1z = r20 * m1x + r21 * m1y + r22 * m1z;
    const float a20 = p0x * p0x + p0y * p0y + p0z * p0z;
    const float a21 = p1x * p1x + p1y * p1y + p1z * p1z;

    __syncthreads();                          // t4s ready

    // Hot loop: uniform LDS reads (broadcast, in-order lgkmcnt -> pipelines),
    // 8 independent min accumulators break the v_min dependency chain.
    float mn0A = 3.4e38f, mn0B = 3.4e38f, mn0C = 3.4e38f, mn0D = 3.4e38f;
    float mn1A = 3.4e38f, mn1B = 3.4e38f, mn1C = 3.4e38f, mn1D = 3.4e38f;
    for (int m = 0; m < NP; m += 4) {
        float4 tA = t4s[m + 0];
        float4 tB = t4s[m + 1];
        float4 tC = t4s[m + 2];
        float4 tD = t4s[m + 3];
        float d0A = fmaf(p0x, tA.x, fmaf(p0y, tA.y, p0z * tA.z));
        float d0B = fmaf(p0x, tB.x, fmaf(p0y, tB.y, p0z * tB.z));
        float d0C = fmaf(p0x, tC.x, fmaf(p0y, tC.y, p0z * tC.z));
        float d0D = fmaf(p0x, tD.x, fmaf(p0y, tD.y, p0z * tD.z));
        float d1A = fmaf(p1x, tA.x, fmaf(p1y, tA.y, p1z * tA.z));
        float d1B = fmaf(p1x, tB.x, fmaf(p1y, tB.y, p1z * tB.z));
        float d1C = fmaf(p1x, tC.x, fmaf(p1y, tC.y, p1z * tC.z));
        float d1D = fmaf(p1x, tD.x, fmaf(p1y, tD.y, p1z * tD.z));
        mn0A = fminf(mn0A, fmaf(-2.f, d0A, tA.w));
        mn0B = fminf(mn0B, fmaf(-2.f, d0B, tB.w));
        mn0C = fminf(mn0C, fmaf(-2.f, d0C, tC.w));
        mn0D = fminf(mn0D, fmaf(-2.f, d0D, tD.w));
        mn1A = fminf(mn1A, fmaf(-2.f, d1A, tA.w));
        mn1B = fminf(mn1B, fmaf(-2.f, d1B, tB.w));
        mn1C = fminf(mn1C, fmaf(-2.f, d1C, tC.w));
        mn1D = fminf(mn1D, fmaf(-2.f, d1D, tD.w));
    }
    const float mn0 = fminf(fminf(mn0A, mn0B), fminf(mn0C, mn0D));
    const float mn1 = fminf(fminf(mn1A, mn1B), fminf(mn1C, mn1D));

    float ssym = 0.f, snon = 0.f;
    {
        float d2 = fmaxf(a20 + mn0, 1e-12f);
        ssym += sqrtf(d2);
        float4 t = t4s[n0];
        float dx = p0x - t.x, dy = p0y - t.y, dz = p0z - t.z;
        snon += sqrtf(dx * dx + dy * dy + dz * dz);
    }
    if (has1) {
        float d2 = fmaxf(a21 + mn1, 1e-12f);
        ssym += sqrtf(d2);
        float4 t = t4s[n1];
        float dx = p1x - t.x, dy = p1y - t.y, dz = p1z - t.z;
        snon += sqrtf(dx * dx + dy * dy + dz * dz);
    }

    // --- block reduce (4 waves) ---
    for (int o = 32; o > 0; o >>= 1) {
        ssym += __shfl_down(ssym, o, 64);
        snon += __shfl_down(snon, o, 64);
    }
    const int wv = tid >> 6, ln = tid & 63;
    if (ln == 0) { red[wv] = ssym; red[4 + wv] = snon; }
    __syncthreads();
    if (tid == 0) {
        out_sym[bid] = red[0] + red[1] + red[2] + red[3];
        out_non[bid] = red[4] + red[5] + red[6] + red[7];
    }
}

__global__ __launch_bounds__(256) void finalize_kernel(
    const float* __restrict__ out_sym, const float* __restrict__ out_non,
    const float* __restrict__ out_reg, const float* __restrict__ out_lt,
    const float* __restrict__ pred_c,
    const unsigned char* __restrict__ symU8, const int* __restrict__ symI,
    const float* __restrict__ diam, float* __restrict__ out)
{
    const int tid = threadIdx.x;
    float s_r = 0.f, s_reg = 0.f, s_t = 0.f;
    for (int i = tid; i < NBLK; i += 256) {
        int b = i / NR;
        // layout-agnostic bool read: true under both 1-byte-bool and int32 storage
        bool sym = (symU8[b] != 0) || (symI[b] != 0);
        float sum = sym ? out_sym[i] : out_non[i];
        float d = sum * (1.0f / NP);
        float c = pred_c[i];
        s_r += (d / (diam[b] * c) + logf(c)) * (1.0f / NR);
        s_reg += out_reg[i];
        s_t += out_lt[i];
    }
    __shared__ float red[12];
    for (int o = 32; o > 0; o >>= 1) {
        s_r += __shfl_down(s_r, o, 64);
        s_reg += __shfl_down(s_reg, o, 64);
        s_t += __shfl_down(s_t, o, 64);
    }
    const int wv = tid >> 6, ln = tid & 63;
    if (ln == 0) { red[wv] = s_r; red[4 + wv] = s_reg; red[8 + wv] = s_t; }
    __syncthreads();
    if (tid == 0) {
        float lr = red[0] + red[1] + red[2] + red[3];
        float lreg = (red[4] + red[5] + red[6] + red[7]) * (1.0f / NBLK);
        float ltv = (red[8] + red[9] + red[10] + red[11]) * (1.0f / NT_ELEMS);
        out[0] = lr + 2.f * lreg + 5.f * ltv;
        out[1] = lr;
        out[2] = lreg;
        out[3] = ltv;
    }
}

extern "C" void kernel_launch(void* const* d_in, const int* in_sizes, int n_in,
                              void* d_out, int out_size, void* d_ws, size_t ws_size,
                              hipStream_t stream) {
    const float* pred_t       = (const float*)d_in[0];
    const float* pred_r       = (const float*)d_in[1];
    const float* pred_c       = (const float*)d_in[2];
    const float* target_r     = (const float*)d_in[3];
    const float* target_t     = (const float*)d_in[4];
    const float* model_points = (const float*)d_in[5];
    const int*   choose       = (const int*)d_in[6];
    const unsigned char* symU8 = (const unsigned char*)d_in[7];
    const int*   symI         = (const int*)d_in[7];
    const float* diam         = (const float*)d_in[8];
    const float* anchors      = (const float*)d_in[9];
    float* out = (float*)d_out;

    char* ws = (char*)d_ws;
    float* o_sym = (float*)ws;                        // 480 floats
    float* o_non = o_sym + NBLK;
    float* o_reg = o_non + NBLK;
    float* o_lt  = o_reg + NBLK;

    main_kernel<<<NBLK, 256, 0, stream>>>(pred_t, pred_r, target_r, target_t,
                                          model_points, choose, anchors,
                                          o_sym, o_non, o_reg, o_lt);
    finalize_kernel<<<1, 256, 0, stream>>>(o_sym, o_non, o_reg, o_lt,
                                           pred_c, symU8, symI, diam, out);
}